// Round 1
// baseline (1177.269 us; speedup 1.0000x reference)
//
#include <hip/hip_runtime.h>
#include <hip/hip_bf16.h>
#include <math.h>

// Problem constants (from reference)
#define B_SZ   1024
#define CIN    96
#define COUT   12
#define LSEQ   32
#define DM     128
#define NBLK   4
#define D_IN   256
#define D_ST   16
#define NH     8
#define HD     32
#define CONVD  288      // D_IN + 2*D_ST
#define EPROJ  552      // 2*D_IN + 2*D_ST + NH
#define EPSV   1e-5f

#define THREADS 512

// LDS arena (floats):
//  s_h   [32*128] = 4096   @ 0        (dir-0 h, pristine)
//  s_hh  [32*128] = 4096   @ 4096     (working residual stream)
//  s_hs  [32*132] = 4224   @ 8192     (padded 132 to break bank conflicts in final phase)
//  s_cv  [32*288] = 9216   @ 12416    (conv output / y; first 4096 alias s_hn)
//  s_z   [32*256] = 8192   @ 21632    (z gate; first 3200 alias buf_t[32*100])
//  s_xbc [32*288] = 9216   @ 29824    (pre-conv xBC)
//  s_dt  [32*8]   = 256    @ 39040
#define SMEM_FLOATS 39296
#define SMEM_BYTES  (SMEM_FLOATS * 4)

__device__ __forceinline__ float siluf(float v) { return v / (1.f + __expf(-v)); }
__device__ __forceinline__ float softplusf_(float v) {
    return (v > 20.f) ? v : log1pf(__expf(v));
}
__device__ __forceinline__ float dot4(float4 a, float4 b) {
    return a.x*b.x + a.y*b.y + a.z*b.z + a.w*b.w;
}

__global__ __launch_bounds__(THREADS, 1)
void mamba_fused(const float* __restrict__ x,
                 const float* __restrict__ buffer,
                 const float* __restrict__ fc_in_w,
                 const float* __restrict__ fc_in_b,
                 const float* __restrict__ blk_norm_w,
                 const float* __restrict__ in_proj_w,
                 const float* __restrict__ conv_w,
                 const float* __restrict__ conv_b,
                 const float* __restrict__ dt_bias,
                 const float* __restrict__ A_log,
                 const float* __restrict__ D_skip,
                 const float* __restrict__ mixer_norm_w,
                 const float* __restrict__ out_proj_w,
                 const float* __restrict__ norm_f_w,
                 const float* __restrict__ fc_out_w,
                 const float* __restrict__ fc_out_b,
                 const float* __restrict__ out_lin_w,
                 const float* __restrict__ out_lin_b,
                 float* __restrict__ out_y,
                 float* __restrict__ out_buf)
{
    const int b   = blockIdx.x;
    const int tid = threadIdx.x;

    extern __shared__ float sm[];
    float* s_h   = sm;            // 4096
    float* s_hh  = sm + 4096;     // 4096
    float* s_hs  = sm + 8192;     // 4224 (stride 132)
    float* s_cv  = sm + 12416;    // 9216
    float* s_hn  = s_cv;          // alias (dead before conv writes)
    float* s_z   = sm + 21632;    // 8192
    float* buf_t = s_z;           // alias (dead before in_proj writes z)
    float* s_xbc = sm + 29824;    // 9216
    float* s_dt  = sm + 39040;    // 256

    // ---- Phase 1: shifted buffer -> buf_t[l][c] (padded stride 100) + out_buf ----
    {
        const float* bufp = buffer + (size_t)b * (CIN * LSEQ);
        const float* xp   = x + (size_t)b * CIN;
        float* obp        = out_buf + (size_t)b * (CIN * LSEQ);
        for (int i = tid; i < CIN * LSEQ; i += THREADS) {
            int c = i >> 5, l = i & 31;
            float v = (l < 31) ? bufp[c * LSEQ + l + 1] : xp[c];
            buf_t[l * 100 + c] = v;
            obp[i] = v;
        }
    }
    __syncthreads();

    // ---- Phase 2: h[l][d] = sum_c buf[l][c] * fc_in_w[d][c] + fc_in_b[d] ----
    {
        int d  = tid & 127;
        int lg = tid >> 7;   // 4 groups of 8 l's
        float acc[8];
#pragma unroll
        for (int j = 0; j < 8; ++j) acc[j] = 0.f;
        const float* wrow = fc_in_w + d * CIN;
        for (int c = 0; c < CIN; c += 4) {
            float4 wv = *(const float4*)(wrow + c);
#pragma unroll
            for (int j = 0; j < 8; ++j) {
                float4 hv = *(const float4*)(buf_t + (lg * 8 + j) * 100 + c);
                acc[j] += dot4(hv, wv);
            }
        }
        float bias = fc_in_b[d];
#pragma unroll
        for (int j = 0; j < 8; ++j) s_h[(lg * 8 + j) * DM + d] = acc[j] + bias;
    }
    __syncthreads();

    for (int dir = 0; dir < 2; ++dir) {
        // init working stream (flip time for dir 1)
        for (int i = tid; i < LSEQ * DM; i += THREADS) {
            int t = i >> 7, d = i & 127;
            int src = dir ? (31 - t) : t;
            s_hh[i] = s_h[src * DM + d];
        }
        __syncthreads();

        for (int lyr = 0; lyr < 2; ++lyr) {
            const int li = dir * 2 + lyr;

            // (a) rmsnorm(s_hh, blk_norm_w[li]) -> s_hn
            {
                int t = tid >> 4, sl = tid & 15;
                const float* row = s_hh + t * DM;
                float v[8]; float ss = 0.f;
#pragma unroll
                for (int j = 0; j < 8; ++j) { v[j] = row[sl * 8 + j]; ss += v[j] * v[j]; }
                ss += __shfl_xor(ss, 1); ss += __shfl_xor(ss, 2);
                ss += __shfl_xor(ss, 4); ss += __shfl_xor(ss, 8);
                float scale = rsqrtf(ss * (1.f / DM) + EPSV);
                const float* nw = blk_norm_w + li * DM;
#pragma unroll
                for (int j = 0; j < 8; ++j) {
                    int d = sl * 8 + j;
                    s_hn[t * DM + d] = v[j] * scale * nw[d];
                }
            }
            __syncthreads();

            // (b) in_proj: main pass, e = tid (0..511), all 32 t's per thread
            {
                const int e = tid;
                const float* wrow = in_proj_w + ((size_t)li * EPROJ + e) * DM;
                float acc[32];
#pragma unroll
                for (int t = 0; t < 32; ++t) acc[t] = 0.f;
                for (int d = 0; d < DM; d += 4) {
                    float4 wv = *(const float4*)(wrow + d);
#pragma unroll
                    for (int t = 0; t < 32; ++t) {
                        float4 hv = *(const float4*)(s_hn + t * DM + d);
                        acc[t] += dot4(hv, wv);
                    }
                }
#pragma unroll
                for (int t = 0; t < 32; ++t) {
                    if (e < D_IN) s_z[t * D_IN + e] = acc[t];
                    else          s_xbc[t * CONVD + (e - D_IN)] = acc[t];
                }
            }
            // (b') remainder e = 512..551 (B/C channels + dt), 8 t-groups of 4
            if (tid < 320) {
                int eo = tid % 40, tg = tid / 40;
                int e = 512 + eo, t0 = tg * 4;
                const float* wrow = in_proj_w + ((size_t)li * EPROJ + e) * DM;
                float acc[4] = {0.f, 0.f, 0.f, 0.f};
                for (int d = 0; d < DM; d += 4) {
                    float4 wv = *(const float4*)(wrow + d);
#pragma unroll
                    for (int j = 0; j < 4; ++j) {
                        float4 hv = *(const float4*)(s_hn + (t0 + j) * DM + d);
                        acc[j] += dot4(hv, wv);
                    }
                }
#pragma unroll
                for (int j = 0; j < 4; ++j) {
                    int t = t0 + j;
                    if (e < 544) {
                        s_xbc[t * CONVD + (e - D_IN)] = acc[j];
                    } else {
                        int hd = e - 544;
                        s_dt[t * NH + hd] = softplusf_(acc[j] + dt_bias[li * NH + hd]);
                    }
                }
            }
            __syncthreads();

            // (c) causal depthwise conv (width 4) + silu -> s_cv
            {
                const float* cw = conv_w + (size_t)li * CONVD * 4;
                const float* cb = conv_b + (size_t)li * CONVD;
                for (int i = tid; i < LSEQ * CONVD; i += THREADS) {
                    int t = i / CONVD, c = i - t * CONVD;
                    float4 wv = *(const float4*)(cw + c * 4);
                    float acc = cb[c];
                    if (t >= 3) {
                        acc += s_xbc[(t - 3) * CONVD + c] * wv.x
                             + s_xbc[(t - 2) * CONVD + c] * wv.y
                             + s_xbc[(t - 1) * CONVD + c] * wv.z
                             + s_xbc[t * CONVD + c] * wv.w;
                    } else {
                        if (t >= 3) acc += s_xbc[(t - 3) * CONVD + c] * wv.x;
                        if (t >= 2) acc += s_xbc[(t - 2) * CONVD + c] * wv.y;
                        if (t >= 1) acc += s_xbc[(t - 1) * CONVD + c] * wv.z;
                        acc += s_xbc[t * CONVD + c] * wv.w;
                    }
                    s_cv[i] = siluf(acc);
                }
            }
            __syncthreads();

            // (d) SSM scan: thread = (head, p); state[16] in registers; y overwrites xs
            if (tid < 256) {
                int hd = tid >> 5, p = tid & 31;
                float a_neg = -__expf(A_log[li * NH + hd]);
                float dsk   = D_skip[li * NH + hd];
                float st[16];
#pragma unroll
                for (int n = 0; n < 16; ++n) st[n] = 0.f;
                for (int t = 0; t < LSEQ; ++t) {
                    float dtv = s_dt[t * NH + hd];
                    float dAv = __expf(dtv * a_neg);
                    float xsv = s_cv[t * CONVD + hd * HD + p];
                    float dtx = dtv * xsv;
                    const float* Bp = s_cv + t * CONVD + D_IN;
                    const float* Cp = Bp + D_ST;
                    float acc = 0.f;
#pragma unroll
                    for (int n = 0; n < 16; ++n) {
                        st[n] = st[n] * dAv + dtx * Bp[n];
                        acc += st[n] * Cp[n];
                    }
                    s_cv[t * CONVD + hd * HD + p] = acc + dsk * xsv;
                }
            }
            __syncthreads();

            // (e) gate with silu(z) + rmsnorm(mixer_norm_w) in-place on s_cv[t][0..255]
            {
                int t = tid >> 4, sl = tid & 15;
                float* row = s_cv + t * CONVD;
                const float* zrow = s_z + t * D_IN;
                float g[16]; float ss = 0.f;
#pragma unroll
                for (int j = 0; j < 16; ++j) {
                    int e = sl * 16 + j;
                    float gv = row[e] * siluf(zrow[e]);
                    g[j] = gv; ss += gv * gv;
                }
                ss += __shfl_xor(ss, 1); ss += __shfl_xor(ss, 2);
                ss += __shfl_xor(ss, 4); ss += __shfl_xor(ss, 8);
                float scale = rsqrtf(ss * (1.f / D_IN) + EPSV);
                const float* mw = mixer_norm_w + li * D_IN;
#pragma unroll
                for (int j = 0; j < 16; ++j) {
                    int e = sl * 16 + j;
                    row[e] = g[j] * scale * mw[e];
                }
            }
            __syncthreads();

            // (f) out_proj + residual: hh[t][d] += sum_e y[t][e] * ow[d][e]
            {
                int d = tid & 127, tg = tid >> 7;   // 4 groups of 8 t's
                const float* wrow = out_proj_w + ((size_t)li * DM + d) * D_IN;
                float acc[8];
#pragma unroll
                for (int j = 0; j < 8; ++j) acc[j] = 0.f;
                for (int e = 0; e < D_IN; e += 4) {
                    float4 wv = *(const float4*)(wrow + e);
#pragma unroll
                    for (int j = 0; j < 8; ++j) {
                        float4 hv = *(const float4*)(s_cv + (tg * 8 + j) * CONVD + e);
                        acc[j] += dot4(hv, wv);
                    }
                }
#pragma unroll
                for (int j = 0; j < 8; ++j) s_hh[(tg * 8 + j) * DM + d] += acc[j];
            }
            __syncthreads();
        } // lyr

        // final per-direction rmsnorm(norm_f_w[dir]) -> accumulate into s_hs (flip for dir 1)
        {
            int t = tid >> 4, sl = tid & 15;
            const float* row = s_hh + t * DM;
            float v[8]; float ss = 0.f;
#pragma unroll
            for (int j = 0; j < 8; ++j) { v[j] = row[sl * 8 + j]; ss += v[j] * v[j]; }
            ss += __shfl_xor(ss, 1); ss += __shfl_xor(ss, 2);
            ss += __shfl_xor(ss, 4); ss += __shfl_xor(ss, 8);
            float scale = rsqrtf(ss * (1.f / DM) + EPSV);
            const float* nw = norm_f_w + dir * DM;
            int tt = dir ? (31 - t) : t;
#pragma unroll
            for (int j = 0; j < 8; ++j) {
                int d = sl * 8 + j;
                float val = v[j] * scale * nw[d];
                if (dir) s_hs[tt * 132 + d] += val;
                else     s_hs[tt * 132 + d] = val;
            }
        }
        __syncthreads();
    } // dir

    // ---- Final: y[b][o] = sum_t out_lin_w[t] * (hs[t] . fc_out_w[o] + fc_out_b[o]) + out_lin_b ----
    if (tid < COUT * LSEQ) {   // 384 threads
        int o = tid >> 5, t = tid & 31;
        const float* wrow = fc_out_w + o * DM;
        const float* hrow = s_hs + t * 132;
        float acc = 0.f;
        for (int d = 0; d < DM; d += 4) {
            float4 wv = *(const float4*)(wrow + d);
            float4 hv = *(const float4*)(hrow + d);
            acc += dot4(hv, wv);
        }
        float part = (acc + fc_out_b[o]) * out_lin_w[t];
        part += __shfl_xor(part, 1);  part += __shfl_xor(part, 2);
        part += __shfl_xor(part, 4);  part += __shfl_xor(part, 8);
        part += __shfl_xor(part, 16);
        if (t == 0) out_y[b * COUT + o] = part + out_lin_b[0];
    }
}

extern "C" void kernel_launch(void* const* d_in, const int* in_sizes, int n_in,
                              void* d_out, int out_size, void* d_ws, size_t ws_size,
                              hipStream_t stream) {
    const float* x            = (const float*)d_in[0];
    const float* buffer      = (const float*)d_in[1];
    const float* fc_in_w     = (const float*)d_in[2];
    const float* fc_in_b     = (const float*)d_in[3];
    const float* blk_norm_w  = (const float*)d_in[4];
    const float* in_proj_w   = (const float*)d_in[5];
    const float* conv_w      = (const float*)d_in[6];
    const float* conv_b      = (const float*)d_in[7];
    const float* dt_bias     = (const float*)d_in[8];
    const float* A_log       = (const float*)d_in[9];
    const float* D_skip      = (const float*)d_in[10];
    const float* mixer_norm_w= (const float*)d_in[11];
    const float* out_proj_w  = (const float*)d_in[12];
    const float* norm_f_w    = (const float*)d_in[13];
    const float* fc_out_w    = (const float*)d_in[14];
    const float* fc_out_b    = (const float*)d_in[15];
    const float* out_lin_w   = (const float*)d_in[16];
    const float* out_lin_b   = (const float*)d_in[17];

    float* out_y   = (float*)d_out;
    float* out_buf = out_y + (size_t)B_SZ * COUT;

    (void)hipFuncSetAttribute((const void*)mamba_fused,
                              hipFuncAttributeMaxDynamicSharedMemorySize,
                              SMEM_BYTES);

    mamba_fused<<<B_SZ, THREADS, SMEM_BYTES, stream>>>(
        x, buffer, fc_in_w, fc_in_b, blk_norm_w, in_proj_w, conv_w, conv_b,
        dt_bias, A_log, D_skip, mixer_norm_w, out_proj_w, norm_f_w,
        fc_out_w, fc_out_b, out_lin_w, out_lin_b, out_y, out_buf);
}

// Round 2
// 428.932 us; speedup vs baseline: 2.7447x; 2.7447x over previous
//
#include <hip/hip_runtime.h>
#include <hip/hip_bf16.h>
#include <math.h>

#define B_SZ   1024
#define CIN    96
#define COUT   12
#define LSEQ   32
#define DM     128
#define D_IN   256
#define D_ST   16
#define NH     8
#define HD     32
#define CONVD  288
#define EPROJ  552
#define EPSV   1e-5f

#define THREADS 512

typedef unsigned short ushort_t;
typedef unsigned int uint_t;
typedef __attribute__((ext_vector_type(8))) short short8;
typedef __attribute__((ext_vector_type(4))) float f32x4;

// ---- fragment-packed bf16 weights (device globals, written by prep kernel each call) ----
#define NIP (4*35*4*512)   // in_proj: 4 layers x 35 ntiles x 4 kchunks x 512
#define NOP (4*8*8*512)    // out_proj: 4 x 8 x 8 x 512
#define NFC (8*3*512)      // fc_in:   8 ntiles x 3 kchunks x 512
__device__ ushort_t g_wip[NIP];
__device__ ushort_t g_wop[NOP];
__device__ ushort_t g_wfc[NFC];

__device__ __forceinline__ ushort_t f2bf(float f) {
    uint_t u = __float_as_uint(f);
    u += 0x7FFFu + ((u >> 16) & 1u);      // RNE
    return (ushort_t)(u >> 16);
}
__device__ __forceinline__ float siluf(float v) { return v / (1.f + __expf(-v)); }
__device__ __forceinline__ float softplusf_(float v) {
    return (v > 20.f) ? v : log1pf(__expf(v));
}
__device__ __forceinline__ float dot4(float4 a, float4 b) {
    return a.x*b.x + a.y*b.y + a.z*b.z + a.w*b.w;
}

__global__ void prep_weights(const float* __restrict__ in_proj_w,
                             const float* __restrict__ out_proj_w,
                             const float* __restrict__ fc_in_w) {
    int idx = blockIdx.x * 256 + threadIdx.x;
    if (idx < NIP) {
        int f = idx >> 9, r = idx & 511;
        int l = r >> 3, j = r & 7;
        int li = f / 140, rem = f - li * 140;
        int nt = rem >> 2, kc = rem & 3;
        int e = nt * 16 + (l & 15);
        int d = kc * 32 + ((l >> 4) << 3) + j;
        float v = (e < EPROJ) ? in_proj_w[((size_t)li * EPROJ + e) * DM + d] : 0.f;
        g_wip[idx] = f2bf(v);
    } else if (idx < NIP + NOP) {
        int i2 = idx - NIP;
        int f = i2 >> 9, r = i2 & 511;
        int l = r >> 3, j = r & 7;
        int li = f >> 6, rem = f & 63;
        int nt = rem >> 3, kc = rem & 7;
        int d = nt * 16 + (l & 15);
        int e = kc * 32 + ((l >> 4) << 3) + j;
        g_wop[i2] = f2bf(out_proj_w[((size_t)li * DM + d) * D_IN + e]);
    } else if (idx < NIP + NOP + NFC) {
        int i2 = idx - NIP - NOP;
        int f = i2 >> 9, r = i2 & 511;
        int l = r >> 3, j = r & 7;
        int nt = f / 3, kc = f - nt * 3;
        int d = nt * 16 + (l & 15);
        int c = kc * 32 + ((l >> 4) << 3) + j;
        g_wfc[i2] = f2bf(fc_in_w[d * CIN + c]);
    }
}

// LDS arena (f32 words):
//  s_h    @ 0      4096            (stride 128)
//  s_hh   @ 4096   4224            (stride 132)
//  s_hs   @ 8320   4224            (stride 132)
//  s_z    @ 12544  8448            (stride 264)   [s_bufb bf16 32x128 aliases]
//  s_dt   @ 20992  256
//  s_xbc  @ 21248  9216            (stride 288)   [s_yb bf16 32x256 aliases]
//  s_hnb  @ 30464  2048 (bf16 32x128)
//  s_cv   @ 30464  9472            (stride 296)   [aliases s_hnb, dead after (b)]
#define SMEM_WORDS 39936
#define SMEM_BYTES (SMEM_WORDS * 4)

__global__ __launch_bounds__(THREADS, 1)
void mamba_fused(const float* __restrict__ x,
                 const float* __restrict__ buffer,
                 const float* __restrict__ fc_in_b,
                 const float* __restrict__ blk_norm_w,
                 const float* __restrict__ conv_w,
                 const float* __restrict__ conv_b,
                 const float* __restrict__ dt_bias,
                 const float* __restrict__ A_log,
                 const float* __restrict__ D_skip,
                 const float* __restrict__ mixer_norm_w,
                 const float* __restrict__ norm_f_w,
                 const float* __restrict__ fc_out_w,
                 const float* __restrict__ fc_out_b,
                 const float* __restrict__ out_lin_w,
                 const float* __restrict__ out_lin_b,
                 float* __restrict__ out_y,
                 float* __restrict__ out_buf)
{
    const int b   = blockIdx.x;
    const int tid = threadIdx.x;

    extern __shared__ float sm[];
    float*    s_h   = sm;
    float*    s_hh  = sm + 4096;
    float*    s_hs  = sm + 8320;
    float*    s_z   = sm + 12544;
    ushort_t* s_bufb= (ushort_t*)(sm + 12544);
    float*    s_dt  = sm + 20992;
    float*    s_xbc = sm + 21248;
    ushort_t* s_yb  = (ushort_t*)(sm + 21248);
    ushort_t* s_hnb = (ushort_t*)(sm + 30464);
    float*    s_cv  = sm + 30464;

    const int wid  = tid >> 6;
    const int lane = tid & 63;
    const int quad = lane >> 4;

    // ---- P1: shifted buffer -> out_buf (f32) + s_bufb (bf16, swizzled) ----
    {
        const float* bufp = buffer + (size_t)b * (CIN * LSEQ);
        const float* xp   = x + (size_t)b * CIN;
        float* obp        = out_buf + (size_t)b * (CIN * LSEQ);
        for (int i = tid; i < CIN * LSEQ; i += THREADS) {
            int c = i >> 5, l2 = i & 31;
            float v = (l2 < 31) ? bufp[i + 1] : xp[c];
            obp[i] = v;
            s_bufb[(l2 * 128 + c) ^ ((l2 & 7) << 3)] = f2bf(v);
        }
    }
    __syncthreads();

    // ---- P2: fc_in via MFMA: h[t][d] = buf . W^T + b ----
    {
        int mt = wid >> 2, row = mt * 16 + (lane & 15);
        const short8* ab = (const short8*)s_bufb;
        short8 a[3];
#pragma unroll
        for (int kc = 0; kc < 3; ++kc)
            a[kc] = ab[(row * 16 + kc * 4 + quad) ^ (row & 7)];
        const ushort_t* wb = g_wfc + lane * 8;
#pragma unroll
        for (int pass = 0; pass < 2; ++pass) {
            int nt = (wid & 3) + pass * 4;
            f32x4 acc = {0.f, 0.f, 0.f, 0.f};
#pragma unroll
            for (int kc = 0; kc < 3; ++kc) {
                short8 bv = *(const short8*)(wb + (nt * 3 + kc) * 512);
                acc = __builtin_amdgcn_mfma_f32_16x16x32_bf16(a[kc], bv, acc, 0, 0, 0);
            }
            int d = nt * 16 + (lane & 15);
            float bias = fc_in_b[d];
#pragma unroll
            for (int r = 0; r < 4; ++r)
                s_h[(mt * 16 + quad * 4 + r) * DM + d] = acc[r] + bias;
        }
    }
    __syncthreads();

    for (int dir = 0; dir < 2; ++dir) {
        for (int i = tid; i < LSEQ * DM; i += THREADS) {
            int t = i >> 7, d = i & 127;
            s_hh[t * 132 + d] = s_h[(dir ? (31 - t) : t) * DM + d];
        }
        __syncthreads();

        for (int lyr = 0; lyr < 2; ++lyr) {
            const int li = dir * 2 + lyr;

            // (a) rmsnorm -> s_hnb (bf16, swizzled)
            {
                int t = tid >> 4, sl = tid & 15;
                const float* row = s_hh + t * 132;
                float v[8]; float ss = 0.f;
#pragma unroll
                for (int j = 0; j < 8; ++j) { v[j] = row[sl * 8 + j]; ss += v[j] * v[j]; }
                ss += __shfl_xor(ss, 1); ss += __shfl_xor(ss, 2);
                ss += __shfl_xor(ss, 4); ss += __shfl_xor(ss, 8);
                float scale = rsqrtf(ss * (1.f / DM) + EPSV);
                const float* nw = blk_norm_w + li * DM;
                uint_t w[4];
#pragma unroll
                for (int p = 0; p < 4; ++p) {
                    int d0 = sl * 8 + p * 2;
                    ushort_t lo = f2bf(v[p * 2] * scale * nw[d0]);
                    ushort_t hi = f2bf(v[p * 2 + 1] * scale * nw[d0 + 1]);
                    w[p] = (uint_t)lo | ((uint_t)hi << 16);
                }
                uint4 q = make_uint4(w[0], w[1], w[2], w[3]);
                ((uint4*)s_hnb)[(t * 16 + sl) ^ (t & 7)] = q;
            }
            __syncthreads();

            // (b) in_proj via MFMA -> s_z / s_xbc / s_dt
            {
                int mt = wid >> 2, row = mt * 16 + (lane & 15);
                const short8* ab = (const short8*)s_hnb;
                short8 a[4];
#pragma unroll
                for (int kc = 0; kc < 4; ++kc)
                    a[kc] = ab[(row * 16 + kc * 4 + quad) ^ (row & 7)];

                const ushort_t* wbase = g_wip + (size_t)li * (35 * 4 * 512) + lane * 8;
                int nt = wid & 3;
                short8 bcur[4], bnext[4];
#pragma unroll
                for (int kc = 0; kc < 4; ++kc)
                    bcur[kc] = *(const short8*)(wbase + (nt * 4 + kc) * 512);
                while (nt < 35) {
                    int nn = nt + 4;
                    if (nn < 35) {
#pragma unroll
                        for (int kc = 0; kc < 4; ++kc)
                            bnext[kc] = *(const short8*)(wbase + (nn * 4 + kc) * 512);
                    }
                    f32x4 acc = {0.f, 0.f, 0.f, 0.f};
#pragma unroll
                    for (int kc = 0; kc < 4; ++kc)
                        acc = __builtin_amdgcn_mfma_f32_16x16x32_bf16(a[kc], bcur[kc], acc, 0, 0, 0);
                    int e = nt * 16 + (lane & 15);
#pragma unroll
                    for (int r = 0; r < 4; ++r) {
                        int t = mt * 16 + quad * 4 + r;
                        float v = acc[r];
                        if (e < D_IN)        s_z[t * 264 + e] = v;
                        else if (e < 544)    s_xbc[t * CONVD + (e - D_IN)] = v;
                        else if (e < EPROJ)  s_dt[t * NH + (e - 544)] =
                                                 softplusf_(v + dt_bias[li * NH + (e - 544)]);
                    }
#pragma unroll
                    for (int kc = 0; kc < 4; ++kc) bcur[kc] = bnext[kc];
                    nt = nn;
                }
            }
            __syncthreads();

            // (c) causal depthwise conv + silu -> s_cv (stride 296)
            {
                const float* cw = conv_w + (size_t)li * CONVD * 4;
                const float* cb = conv_b + (size_t)li * CONVD;
                for (int i = tid; i < LSEQ * CONVD; i += THREADS) {
                    int t = i / CONVD, c = i - t * CONVD;
                    float4 wv = *(const float4*)(cw + c * 4);
                    float acc = cb[c];
                    if (t >= 3) {
                        acc += s_xbc[(t - 3) * CONVD + c] * wv.x
                             + s_xbc[(t - 2) * CONVD + c] * wv.y
                             + s_xbc[(t - 1) * CONVD + c] * wv.z
                             + s_xbc[t * CONVD + c] * wv.w;
                    } else {
                        if (t >= 2) acc += s_xbc[(t - 2) * CONVD + c] * wv.y;
                        if (t >= 1) acc += s_xbc[(t - 1) * CONVD + c] * wv.z;
                        acc += s_xbc[t * CONVD + c] * wv.w;
                    }
                    s_cv[t * 296 + c] = siluf(acc);
                }
            }
            __syncthreads();

            // (d) SSM scan
            if (tid < 256) {
                int hd = tid >> 5, p = tid & 31;
                float a_neg = -__expf(A_log[li * NH + hd]);
                float dsk   = D_skip[li * NH + hd];
                float st[16];
#pragma unroll
                for (int n = 0; n < 16; ++n) st[n] = 0.f;
                for (int t = 0; t < LSEQ; ++t) {
                    float dtv = s_dt[t * NH + hd];
                    float dAv = __expf(dtv * a_neg);
                    float xsv = s_cv[t * 296 + hd * HD + p];
                    float dtx = dtv * xsv;
                    const float* Bp = s_cv + t * 296 + D_IN;
                    const float* Cp = Bp + D_ST;
                    float acc0 = 0.f, acc1 = 0.f;
#pragma unroll
                    for (int n = 0; n < 8; ++n) {
                        st[n] = st[n] * dAv + dtx * Bp[n];
                        acc0 += st[n] * Cp[n];
                    }
#pragma unroll
                    for (int n = 8; n < 16; ++n) {
                        st[n] = st[n] * dAv + dtx * Bp[n];
                        acc1 += st[n] * Cp[n];
                    }
                    s_cv[t * 296 + hd * HD + p] = acc0 + acc1 + dsk * xsv;
                }
            }
            __syncthreads();

            // (e) gate + rmsnorm -> s_yb (bf16, swizzled)
            {
                int t = tid >> 4, sl = tid & 15;
                const float* yrow = s_cv + t * 296;
                const float* zrow = s_z + t * 264;
                float g[16]; float ss = 0.f;
#pragma unroll
                for (int j = 0; j < 16; ++j) {
                    int e = j * 16 + sl;
                    float gv = yrow[e] * siluf(zrow[e]);
                    g[j] = gv; ss += gv * gv;
                }
                ss += __shfl_xor(ss, 1); ss += __shfl_xor(ss, 2);
                ss += __shfl_xor(ss, 4); ss += __shfl_xor(ss, 8);
                float scale = rsqrtf(ss * (1.f / D_IN) + EPSV);
                const float* mw = mixer_norm_w + li * D_IN;
#pragma unroll
                for (int j = 0; j < 16; ++j) {
                    int e = j * 16 + sl;
                    s_yb[(t * 256 + e) ^ ((t & 7) << 3)] = f2bf(g[j] * scale * mw[e]);
                }
            }
            __syncthreads();

            // (f) out_proj via MFMA, residual into s_hh
            {
                int mt = wid >> 2, row = mt * 16 + (lane & 15);
                const short8* yb = (const short8*)s_yb;
                short8 a[8];
#pragma unroll
                for (int kc = 0; kc < 8; ++kc)
                    a[kc] = yb[(row * 32 + kc * 4 + quad) ^ (row & 7)];
                const ushort_t* wb = g_wop + (size_t)li * (8 * 8 * 512) + lane * 8;
#pragma unroll
                for (int pass = 0; pass < 2; ++pass) {
                    int nt = (wid & 3) + pass * 4;
                    f32x4 acc = {0.f, 0.f, 0.f, 0.f};
#pragma unroll
                    for (int kc = 0; kc < 8; ++kc) {
                        short8 bv = *(const short8*)(wb + (nt * 8 + kc) * 512);
                        acc = __builtin_amdgcn_mfma_f32_16x16x32_bf16(a[kc], bv, acc, 0, 0, 0);
                    }
                    int d = nt * 16 + (lane & 15);
#pragma unroll
                    for (int r = 0; r < 4; ++r)
                        s_hh[(mt * 16 + quad * 4 + r) * 132 + d] += acc[r];
                }
            }
            __syncthreads();
        } // lyr

        // final per-direction rmsnorm -> s_hs (accumulate for dir 1, time-flipped)
        {
            int t = tid >> 4, sl = tid & 15;
            const float* row = s_hh + t * 132;
            float v[8]; float ss = 0.f;
#pragma unroll
            for (int j = 0; j < 8; ++j) { v[j] = row[sl * 8 + j]; ss += v[j] * v[j]; }
            ss += __shfl_xor(ss, 1); ss += __shfl_xor(ss, 2);
            ss += __shfl_xor(ss, 4); ss += __shfl_xor(ss, 8);
            float scale = rsqrtf(ss * (1.f / DM) + EPSV);
            const float* nw = norm_f_w + dir * DM;
            int tt = dir ? (31 - t) : t;
#pragma unroll
            for (int j = 0; j < 8; ++j) {
                int d = sl * 8 + j;
                float val = v[j] * scale * nw[d];
                if (dir) s_hs[tt * 132 + d] += val;
                else     s_hs[tt * 132 + d] = val;
            }
        }
        __syncthreads();
    } // dir

    // ---- final: fc_out + out_lin reduction ----
    if (tid < COUT * LSEQ) {
        int o = tid >> 5, t = tid & 31;
        const float* wrow = fc_out_w + o * DM;
        const float* hrow = s_hs + t * 132;
        float acc = 0.f;
        for (int d = 0; d < DM; d += 4) {
            float4 wv = *(const float4*)(wrow + d);
            float4 hv = *(const float4*)(hrow + d);
            acc += dot4(hv, wv);
        }
        float part = (acc + fc_out_b[o]) * out_lin_w[t];
        part += __shfl_xor(part, 1);  part += __shfl_xor(part, 2);
        part += __shfl_xor(part, 4);  part += __shfl_xor(part, 8);
        part += __shfl_xor(part, 16);
        if (t == 0) out_y[b * COUT + o] = part + out_lin_b[0];
    }
}

extern "C" void kernel_launch(void* const* d_in, const int* in_sizes, int n_in,
                              void* d_out, int out_size, void* d_ws, size_t ws_size,
                              hipStream_t stream) {
    const float* x            = (const float*)d_in[0];
    const float* buffer      = (const float*)d_in[1];
    const float* fc_in_w     = (const float*)d_in[2];
    const float* fc_in_b     = (const float*)d_in[3];
    const float* blk_norm_w  = (const float*)d_in[4];
    const float* in_proj_w   = (const float*)d_in[5];
    const float* conv_w      = (const float*)d_in[6];
    const float* conv_b      = (const float*)d_in[7];
    const float* dt_bias     = (const float*)d_in[8];
    const float* A_log       = (const float*)d_in[9];
    const float* D_skip      = (const float*)d_in[10];
    const float* mixer_norm_w= (const float*)d_in[11];
    const float* out_proj_w  = (const float*)d_in[12];
    const float* norm_f_w    = (const float*)d_in[13];
    const float* fc_out_w    = (const float*)d_in[14];
    const float* fc_out_b    = (const float*)d_in[15];
    const float* out_lin_w   = (const float*)d_in[16];
    const float* out_lin_b   = (const float*)d_in[17];

    float* out_y   = (float*)d_out;
    float* out_buf = out_y + (size_t)B_SZ * COUT;

    prep_weights<<<(NIP + NOP + NFC + 255) / 256, 256, 0, stream>>>(
        in_proj_w, out_proj_w, fc_in_w);

    (void)hipFuncSetAttribute((const void*)mamba_fused,
                              hipFuncAttributeMaxDynamicSharedMemorySize,
                              SMEM_BYTES);

    mamba_fused<<<B_SZ, THREADS, SMEM_BYTES, stream>>>(
        x, buffer, fc_in_b, blk_norm_w, conv_w, conv_b,
        dt_bias, A_log, D_skip, mixer_norm_w, norm_f_w,
        fc_out_w, fc_out_b, out_lin_w, out_lin_b, out_y, out_buf);
}

// Round 3
// 301.262 us; speedup vs baseline: 3.9078x; 1.4238x over previous
//
#include <hip/hip_runtime.h>
#include <hip/hip_bf16.h>
#include <math.h>

#define B_SZ   1024
#define CIN    96
#define COUT   12
#define LSEQ   32
#define DM     128
#define D_IN   256
#define D_ST   16
#define NH     8
#define HD     32
#define CONVD  288
#define EPROJ  552
#define EPSV   1e-5f

#define THREADS 512

typedef unsigned short ushort_t;
typedef unsigned int uint_t;
typedef __attribute__((ext_vector_type(8))) short short8;
typedef __attribute__((ext_vector_type(4))) float f32x4;

// ---- fragment-packed bf16 weights (device globals, rewritten each call) ----
#define NIP (4*35*4*512)   // in_proj: 4 layers x 35 ntiles x 4 kchunks x 512
#define NOP (4*8*8*512)    // out_proj: 4 x 8 x 8 x 512
#define NFC (8*3*512)      // fc_in:   8 ntiles x 3 kchunks x 512
__device__ ushort_t g_wip[NIP];
__device__ ushort_t g_wop[NOP];
__device__ ushort_t g_wfc[NFC];

__device__ __forceinline__ ushort_t f2bf(float f) {
    uint_t u = __float_as_uint(f);
    u += 0x7FFFu + ((u >> 16) & 1u);      // RNE
    return (ushort_t)(u >> 16);
}
__device__ __forceinline__ float bf2f(ushort_t u) {
    return __uint_as_float((uint_t)u << 16);
}
__device__ __forceinline__ float siluf(float v) { return v / (1.f + __expf(-v)); }
__device__ __forceinline__ float softplusf_(float v) {
    return (v > 20.f) ? v : log1pf(__expf(v));
}

__global__ void prep_weights(const float* __restrict__ in_proj_w,
                             const float* __restrict__ out_proj_w,
                             const float* __restrict__ fc_in_w) {
    int idx = blockIdx.x * 256 + threadIdx.x;
    if (idx < NIP) {
        int f = idx >> 9, r = idx & 511;
        int l = r >> 3, j = r & 7;
        int li = f / 140, rem = f - li * 140;
        int nt = rem >> 2, kc = rem & 3;
        int e = nt * 16 + (l & 15);
        int d = kc * 32 + ((l >> 4) << 3) + j;
        float v = (e < EPROJ) ? in_proj_w[((size_t)li * EPROJ + e) * DM + d] : 0.f;
        g_wip[idx] = f2bf(v);
    } else if (idx < NIP + NOP) {
        int i2 = idx - NIP;
        int f = i2 >> 9, r = i2 & 511;
        int l = r >> 3, j = r & 7;
        int li = f >> 6, rem = f & 63;
        int nt = rem >> 3, kc = rem & 7;
        int d = nt * 16 + (l & 15);
        int e = kc * 32 + ((l >> 4) << 3) + j;
        g_wop[i2] = f2bf(out_proj_w[((size_t)li * DM + d) * D_IN + e]);
    } else if (idx < NIP + NOP + NFC) {
        int i2 = idx - NIP - NOP;
        int f = i2 >> 9, r = i2 & 511;
        int l = r >> 3, j = r & 7;
        int nt = f / 3, kc = f - nt * 3;
        int d = nt * 16 + (l & 15);
        int c = kc * 32 + ((l >> 4) << 3) + j;
        g_wfc[i2] = f2bf(fc_in_w[d * CIN + c]);
    }
}

// ---- LDS arena (f32 words), total 20096 words = 80384 B  (< 80 KiB -> 2 blocks/CU) ----
//  s_hh   @ 0      4224   f32 [32][132]      residual stream
//  s_hsb  @ 4224   2176   bf16 [32][136]     cross-dir accumulator
//  s_bufb @ 6400   2048   bf16 [32][128]     fc_in input fragments (persistent)
//  s_hnb  @ 8448   2048   bf16 [32][128]     normed h fragments (granule-swizzled)
//  s_zyb  @ 10496  4096   bf16 [32][256]     z gate, later gated y (swizzled, aliased)
//  s_xb   @ 14592  4096   bf16 [32][256]     x part of xBC; conv in-place; y after scan
//  s_bcf  @ 18688  1152   f32 [32][36]       B,C channels (f32 end-to-end, conv in-place)
//  s_dt   @ 19840  256    f32 [32][8]
#define OFF_HH   0
#define OFF_HSB  4224
#define OFF_BUFB 6400
#define OFF_HNB  8448
#define OFF_ZYB  10496
#define OFF_XB   14592
#define OFF_BCF  18688
#define OFF_DT   19840
#define SMEM_WORDS 20096
#define SMEM_BYTES (SMEM_WORDS * 4)

__global__ __launch_bounds__(THREADS, 4)
void mamba_fused(const float* __restrict__ x,
                 const float* __restrict__ buffer,
                 const float* __restrict__ fc_in_b,
                 const float* __restrict__ blk_norm_w,
                 const float* __restrict__ conv_w,
                 const float* __restrict__ conv_b,
                 const float* __restrict__ dt_bias,
                 const float* __restrict__ A_log,
                 const float* __restrict__ D_skip,
                 const float* __restrict__ mixer_norm_w,
                 const float* __restrict__ norm_f_w,
                 const float* __restrict__ fc_out_w,
                 const float* __restrict__ fc_out_b,
                 const float* __restrict__ out_lin_w,
                 const float* __restrict__ out_lin_b,
                 float* __restrict__ out_y,
                 float* __restrict__ out_buf)
{
    const int b   = blockIdx.x;
    const int tid = threadIdx.x;

    extern __shared__ float sm[];
    float*    s_hh  = sm + OFF_HH;
    ushort_t* s_hsb = (ushort_t*)(sm + OFF_HSB);
    ushort_t* s_bufb= (ushort_t*)(sm + OFF_BUFB);
    ushort_t* s_hnb = (ushort_t*)(sm + OFF_HNB);
    ushort_t* s_zyb = (ushort_t*)(sm + OFF_ZYB);
    ushort_t* s_xb  = (ushort_t*)(sm + OFF_XB);
    float*    s_bcf = sm + OFF_BCF;
    float*    s_dt  = sm + OFF_DT;

    const int wid  = tid >> 6;
    const int lane = tid & 63;
    const int quad = lane >> 4;

    // ---- P1: shifted buffer -> out_buf (f32) + s_bufb (bf16, swizzled) ----
    {
        const float* bufp = buffer + (size_t)b * (CIN * LSEQ);
        const float* xp   = x + (size_t)b * CIN;
        float* obp        = out_buf + (size_t)b * (CIN * LSEQ);
        for (int i = tid; i < CIN * LSEQ; i += THREADS) {
            int c = i >> 5, l2 = i & 31;
            float v = (l2 < 31) ? bufp[i + 1] : xp[c];
            obp[i] = v;
            s_bufb[(l2 * 128 + c) ^ ((l2 & 7) << 3)] = f2bf(v);
        }
    }
    __syncthreads();

    for (int dir = 0; dir < 2; ++dir) {
        // ---- fc_in via MFMA (recomputed per dir), write s_hh time-flipped ----
        {
            int mt = wid >> 2, row = mt * 16 + (lane & 15);
            const short8* ab = (const short8*)s_bufb;
            short8 a[3];
#pragma unroll
            for (int kc = 0; kc < 3; ++kc)
                a[kc] = ab[(row * 16 + kc * 4 + quad) ^ (row & 7)];
            const ushort_t* wb = g_wfc + lane * 8;
#pragma unroll
            for (int pass = 0; pass < 2; ++pass) {
                int nt = (wid & 3) + pass * 4;
                f32x4 acc = {0.f, 0.f, 0.f, 0.f};
#pragma unroll
                for (int kc = 0; kc < 3; ++kc) {
                    short8 bv = *(const short8*)(wb + (nt * 3 + kc) * 512);
                    acc = __builtin_amdgcn_mfma_f32_16x16x32_bf16(a[kc], bv, acc, 0, 0, 0);
                }
                int d = nt * 16 + (lane & 15);
                float bias = fc_in_b[d];
#pragma unroll
                for (int r = 0; r < 4; ++r) {
                    int t = mt * 16 + quad * 4 + r;
                    int tt = dir ? (31 - t) : t;
                    s_hh[tt * 132 + d] = acc[r] + bias;
                }
            }
        }
        __syncthreads();

        for (int lyr = 0; lyr < 2; ++lyr) {
            const int li = dir * 2 + lyr;

            // (a) rmsnorm(s_hh) -> s_hnb (bf16, granule-swizzled)
            {
                int t = tid >> 4, sl = tid & 15;
                const float* row = s_hh + t * 132;
                float v[8]; float ss = 0.f;
#pragma unroll
                for (int j = 0; j < 8; ++j) { v[j] = row[sl * 8 + j]; ss += v[j] * v[j]; }
                ss += __shfl_xor(ss, 1); ss += __shfl_xor(ss, 2);
                ss += __shfl_xor(ss, 4); ss += __shfl_xor(ss, 8);
                float scale = rsqrtf(ss * (1.f / DM) + EPSV);
                const float* nw = blk_norm_w + li * DM;
                uint_t w[4];
#pragma unroll
                for (int p = 0; p < 4; ++p) {
                    int d0 = sl * 8 + p * 2;
                    ushort_t lo = f2bf(v[p * 2] * scale * nw[d0]);
                    ushort_t hi = f2bf(v[p * 2 + 1] * scale * nw[d0 + 1]);
                    w[p] = (uint_t)lo | ((uint_t)hi << 16);
                }
                uint4 q = make_uint4(w[0], w[1], w[2], w[3]);
                ((uint4*)s_hnb)[(t * 16 + sl) ^ (t & 7)] = q;
            }
            __syncthreads();

            // (b) in_proj via MFMA -> s_zyb (z) / s_xb (x) / s_bcf (B,C) / s_dt
            {
                int mt = wid >> 2, row = mt * 16 + (lane & 15);
                const short8* ab = (const short8*)s_hnb;
                short8 a[4];
#pragma unroll
                for (int kc = 0; kc < 4; ++kc)
                    a[kc] = ab[(row * 16 + kc * 4 + quad) ^ (row & 7)];

                const ushort_t* wbase = g_wip + (size_t)li * (35 * 4 * 512) + lane * 8;
                int nt = wid & 3;
                short8 bcur[4], bnext[4];
#pragma unroll
                for (int kc = 0; kc < 4; ++kc)
                    bcur[kc] = *(const short8*)(wbase + (nt * 4 + kc) * 512);
                while (nt < 35) {
                    int nn = nt + 4;
                    if (nn < 35) {
#pragma unroll
                        for (int kc = 0; kc < 4; ++kc)
                            bnext[kc] = *(const short8*)(wbase + (nn * 4 + kc) * 512);
                    }
                    f32x4 acc = {0.f, 0.f, 0.f, 0.f};
#pragma unroll
                    for (int kc = 0; kc < 4; ++kc)
                        acc = __builtin_amdgcn_mfma_f32_16x16x32_bf16(a[kc], bcur[kc], acc, 0, 0, 0);
                    int e = nt * 16 + (lane & 15);
#pragma unroll
                    for (int r = 0; r < 4; ++r) {
                        int t = mt * 16 + quad * 4 + r;
                        float v = acc[r];
                        if (e < D_IN) {
                            s_zyb[(t * 256 + e) ^ ((t & 7) << 3)] = f2bf(v);
                        } else if (e < 512) {
                            s_xb[t * 256 + (e - D_IN)] = f2bf(v);
                        } else if (e < 544) {
                            s_bcf[t * 36 + (e - 512)] = v;
                        } else if (e < EPROJ) {
                            s_dt[t * NH + (e - 544)] =
                                softplusf_(v + dt_bias[li * NH + (e - 544)]);
                        }
                    }
#pragma unroll
                    for (int kc = 0; kc < 4; ++kc) bcur[kc] = bnext[kc];
                    nt = nn;
                }
            }
            __syncthreads();

            // (c) causal depthwise conv + silu, IN PLACE (windowed, per-channel thread)
            if (tid < CONVD) {
                const int c = tid;
                const float4 wv = *(const float4*)(conv_w + ((size_t)li * CONVD + c) * 4);
                const float bias = conv_b[li * CONVD + c];
                if (c < D_IN) {
                    float xin[32];
#pragma unroll
                    for (int t = 0; t < 32; ++t) xin[t] = bf2f(s_xb[t * 256 + c]);
                    float w0 = 0.f, w1 = 0.f, w2 = 0.f;
#pragma unroll
                    for (int t = 0; t < 32; ++t) {
                        float cur = xin[t];
                        float acc = bias + w0 * wv.x + w1 * wv.y + w2 * wv.z + cur * wv.w;
                        s_xb[t * 256 + c] = f2bf(siluf(acc));
                        w0 = w1; w1 = w2; w2 = cur;
                    }
                } else {
                    const int ch = c - D_IN;
                    float xin[32];
#pragma unroll
                    for (int t = 0; t < 32; ++t) xin[t] = s_bcf[t * 36 + ch];
                    float w0 = 0.f, w1 = 0.f, w2 = 0.f;
#pragma unroll
                    for (int t = 0; t < 32; ++t) {
                        float cur = xin[t];
                        float acc = bias + w0 * wv.x + w1 * wv.y + w2 * wv.z + cur * wv.w;
                        s_bcf[t * 36 + ch] = siluf(acc);
                        w0 = w1; w1 = w2; w2 = cur;
                    }
                }
            }
            __syncthreads();

            // (d) SSM scan: thread=(head,p); B/C f32 broadcast loads; y -> s_xb (bf16)
            if (tid < 256) {
                int hd = tid >> 5, p = tid & 31;
                float a_neg = -__expf(A_log[li * NH + hd]);
                float dsk   = D_skip[li * NH + hd];
                float st[16];
#pragma unroll
                for (int n = 0; n < 16; ++n) st[n] = 0.f;
#pragma unroll
                for (int t = 0; t < 32; ++t) {
                    float dtv = s_dt[t * NH + hd];
                    float dAv = __expf(dtv * a_neg);
                    float xsv = bf2f(s_xb[t * 256 + hd * HD + p]);
                    float dtx = dtv * xsv;
                    const f32x4* Bp = (const f32x4*)(s_bcf + t * 36);
                    const f32x4* Cp = (const f32x4*)(s_bcf + t * 36 + 16);
                    float acc0 = 0.f, acc1 = 0.f, acc2 = 0.f, acc3 = 0.f;
#pragma unroll
                    for (int q = 0; q < 4; ++q) {
                        f32x4 Bv = Bp[q], Cv = Cp[q];
                        float* s4 = st + q * 4;
                        s4[0] = s4[0] * dAv + dtx * Bv.x;  acc0 += s4[0] * Cv.x;
                        s4[1] = s4[1] * dAv + dtx * Bv.y;  acc1 += s4[1] * Cv.y;
                        s4[2] = s4[2] * dAv + dtx * Bv.z;  acc2 += s4[2] * Cv.z;
                        s4[3] = s4[3] * dAv + dtx * Bv.w;  acc3 += s4[3] * Cv.w;
                    }
                    float y = (acc0 + acc1) + (acc2 + acc3) + dsk * xsv;
                    s_xb[t * 256 + hd * HD + p] = f2bf(y);
                }
            }
            __syncthreads();

            // (e) gate with silu(z) + rmsnorm -> s_zyb (element-in-place over z)
            {
                int t = tid >> 4, sl = tid & 15;
                float g[16]; float ss = 0.f;
#pragma unroll
                for (int j = 0; j < 16; ++j) {
                    int e = j * 16 + sl;
                    float yv = bf2f(s_xb[t * 256 + e]);
                    float zv = bf2f(s_zyb[(t * 256 + e) ^ ((t & 7) << 3)]);
                    float gv = yv * siluf(zv);
                    g[j] = gv; ss += gv * gv;
                }
                ss += __shfl_xor(ss, 1); ss += __shfl_xor(ss, 2);
                ss += __shfl_xor(ss, 4); ss += __shfl_xor(ss, 8);
                float scale = rsqrtf(ss * (1.f / D_IN) + EPSV);
                const float* mw = mixer_norm_w + li * D_IN;
#pragma unroll
                for (int j = 0; j < 16; ++j) {
                    int e = j * 16 + sl;
                    s_zyb[(t * 256 + e) ^ ((t & 7) << 3)] = f2bf(g[j] * scale * mw[e]);
                }
            }
            __syncthreads();

            // (f) out_proj via MFMA, residual accumulate into s_hh
            {
                int mt = wid >> 2, row = mt * 16 + (lane & 15);
                const short8* yb = (const short8*)s_zyb;
                short8 a[8];
#pragma unroll
                for (int kc = 0; kc < 8; ++kc)
                    a[kc] = yb[(row * 32 + kc * 4 + quad) ^ (row & 7)];
                const ushort_t* wb = g_wop + (size_t)li * (8 * 8 * 512) + lane * 8;
#pragma unroll
                for (int pass = 0; pass < 2; ++pass) {
                    int nt = (wid & 3) + pass * 4;
                    f32x4 acc = {0.f, 0.f, 0.f, 0.f};
#pragma unroll
                    for (int kc = 0; kc < 8; ++kc) {
                        short8 bv = *(const short8*)(wb + (nt * 8 + kc) * 512);
                        acc = __builtin_amdgcn_mfma_f32_16x16x32_bf16(a[kc], bv, acc, 0, 0, 0);
                    }
                    int d = nt * 16 + (lane & 15);
#pragma unroll
                    for (int r = 0; r < 4; ++r)
                        s_hh[(mt * 16 + quad * 4 + r) * 132 + d] += acc[r];
                }
            }
            __syncthreads();
        } // lyr

        // final per-direction rmsnorm -> s_hsb (bf16; dir1 accumulates, time-flipped)
        {
            int t = tid >> 4, sl = tid & 15;
            const float* row = s_hh + t * 132;
            float v[8]; float ss = 0.f;
#pragma unroll
            for (int j = 0; j < 8; ++j) { v[j] = row[sl * 8 + j]; ss += v[j] * v[j]; }
            ss += __shfl_xor(ss, 1); ss += __shfl_xor(ss, 2);
            ss += __shfl_xor(ss, 4); ss += __shfl_xor(ss, 8);
            float scale = rsqrtf(ss * (1.f / DM) + EPSV);
            const float* nw = norm_f_w + dir * DM;
            int tt = dir ? (31 - t) : t;
#pragma unroll
            for (int j = 0; j < 8; ++j) {
                int d = sl * 8 + j;
                float val = v[j] * scale * nw[d];
                if (dir) {
                    float prev = bf2f(s_hsb[tt * 136 + d]);
                    s_hsb[tt * 136 + d] = f2bf(prev + val);
                } else {
                    s_hsb[tt * 136 + d] = f2bf(val);
                }
            }
        }
        __syncthreads();
    } // dir

    // ---- final: fc_out + out_lin reduction over t ----
    if (tid < COUT * LSEQ) {
        int o = tid >> 5, t = tid & 31;
        const float* wrow = fc_out_w + o * DM;
        const ushort_t* hrow = s_hsb + t * 136;
        float acc = 0.f;
#pragma unroll
        for (int d = 0; d < DM; d += 4) {
            float4 wv = *(const float4*)(wrow + d);
            acc += bf2f(hrow[d])     * wv.x + bf2f(hrow[d + 1]) * wv.y
                 + bf2f(hrow[d + 2]) * wv.z + bf2f(hrow[d + 3]) * wv.w;
        }
        float part = (acc + fc_out_b[o]) * out_lin_w[t];
        part += __shfl_xor(part, 1);  part += __shfl_xor(part, 2);
        part += __shfl_xor(part, 4);  part += __shfl_xor(part, 8);
        part += __shfl_xor(part, 16);
        if (t == 0) out_y[b * COUT + o] = part + out_lin_b[0];
    }
}

extern "C" void kernel_launch(void* const* d_in, const int* in_sizes, int n_in,
                              void* d_out, int out_size, void* d_ws, size_t ws_size,
                              hipStream_t stream) {
    const float* x            = (const float*)d_in[0];
    const float* buffer      = (const float*)d_in[1];
    const float* fc_in_w     = (const float*)d_in[2];
    const float* fc_in_b     = (const float*)d_in[3];
    const float* blk_norm_w  = (const float*)d_in[4];
    const float* in_proj_w   = (const float*)d_in[5];
    const float* conv_w      = (const float*)d_in[6];
    const float* conv_b      = (const float*)d_in[7];
    const float* dt_bias     = (const float*)d_in[8];
    const float* A_log       = (const float*)d_in[9];
    const float* D_skip      = (const float*)d_in[10];
    const float* mixer_norm_w= (const float*)d_in[11];
    const float* out_proj_w  = (const float*)d_in[12];
    const float* norm_f_w    = (const float*)d_in[13];
    const float* fc_out_w    = (const float*)d_in[14];
    const float* fc_out_b    = (const float*)d_in[15];
    const float* out_lin_w   = (const float*)d_in[16];
    const float* out_lin_b   = (const float*)d_in[17];

    float* out_y   = (float*)d_out;
    float* out_buf = out_y + (size_t)B_SZ * COUT;

    prep_weights<<<(NIP + NOP + NFC + 255) / 256, 256, 0, stream>>>(
        in_proj_w, out_proj_w, fc_in_w);

    (void)hipFuncSetAttribute((const void*)mamba_fused,
                              hipFuncAttributeMaxDynamicSharedMemorySize,
                              SMEM_BYTES);

    mamba_fused<<<B_SZ, THREADS, SMEM_BYTES, stream>>>(
        x, buffer, fc_in_b, blk_norm_w, conv_w, conv_b,
        dt_bias, A_log, D_skip, mixer_norm_w, norm_f_w,
        fc_out_w, fc_out_b, out_lin_w, out_lin_b, out_y, out_buf);
}